// Round 10
// baseline (229.393 us; speedup 1.0000x reference)
//
#include <hip/hip_runtime.h>
#include <math.h>

#define NPTS 4096
#define NB   8
#define NC   64
#define KSEL 30
#define NROWS (NB * NPTS * KSEL)   // 983040
#define CNT_F 983040.0f
#define P23_BLOCKS 480
#define P23_QSTRIDE (P23_BLOCKS * 256)  // 122880 quads; x2 = 245760 quads = NROWS/4

static __device__ __forceinline__ unsigned long long shfl_xor_u64(unsigned long long v, int lx) {
    int lo = __shfl_xor((int)(unsigned)(v & 0xFFFFFFFFULL), lx, 64);
    int hi = __shfl_xor((int)(unsigned)(v >> 32), lx, 64);
    return ((unsigned long long)(unsigned)hi << 32) | (unsigned)lo;
}

// ---------------------------------------------------------------------------
// helpers: per-block reduction of 64-spread accumulator slots, BN param math
// ---------------------------------------------------------------------------
template <int NM>
static __device__ __forceinline__ void slot_reduce(const float* __restrict__ acc,
                                                   float* __restrict__ sSum, int tid) {
    if (tid < 64) {
        float pm[NM];
#pragma unroll
        for (int m = 0; m < NM; ++m) pm[m] = acc[m * 64 + tid];
#pragma unroll
        for (int o = 32; o > 0; o >>= 1) {
#pragma unroll
            for (int m = 0; m < NM; ++m) pm[m] += __shfl_xor(pm[m], o, 64);
        }
        if (tid == 0) {
#pragma unroll
            for (int m = 0; m < NM; ++m) sSum[m] = pm[m];
        }
    }
}

static __device__ __forceinline__ void bn1_params(const float* __restrict__ sSum,
                                                  const float* __restrict__ W1,
                                                  const float* __restrict__ g1,
                                                  const float* __restrict__ b1,
                                                  float* __restrict__ sPar, int tid) {
    if (tid < 6) {
        const float invN = 1.0f / CNT_F;
        const float m0 = sSum[0] * invN, m1 = sSum[1] * invN, m2 = sSum[2] * invN;
        const float E00 = sSum[3] * invN, E01 = sSum[4] * invN, E02 = sSum[5] * invN;
        const float E11 = sSum[6] * invN, E12 = sSum[7] * invN, E22 = sSum[8] * invN;
        const float* w = W1 + tid * 6;
        const float third = (w[3] + w[4] + w[5]) * (1.0f / 3.0f);
        const float a0 = w[0] + w[3] - third;
        const float a1 = w[1] + w[4] - third;
        const float a2 = w[2] + w[5] - third;
        const float mu = a0 * m0 + a1 * m1 + a2 * m2;
        const float E2 = a0 * a0 * E00 + a1 * a1 * E11 + a2 * a2 * E22 +
                         2.0f * (a0 * a1 * E01 + a0 * a2 * E02 + a1 * a2 * E12);
        const float var = E2 - mu * mu;
        const float sc = g1[tid] / sqrtf(var + 1e-5f);
        sPar[tid] = sc;
        sPar[6 + tid] = b1[tid] - mu * sc;
    }
}

static __device__ __forceinline__ void bn2_params(const float* __restrict__ sSum,
                                                  const float* __restrict__ W2,
                                                  const float* __restrict__ g2,
                                                  const float* __restrict__ b2,
                                                  float* __restrict__ sPar, int tid) {
    if (tid < 3) {
        const float invN = 1.0f / CNT_F;
        float Eh[6];
#pragma unroll
        for (int d = 0; d < 6; ++d) Eh[d] = sSum[d] * invN;
        float M[6][6];
        int q = 6;
#pragma unroll
        for (int a2 = 0; a2 < 6; ++a2)
#pragma unroll
            for (int b2_ = a2; b2_ < 6; ++b2_) {
                const float v = sSum[q++] * invN;
                M[a2][b2_] = v; M[b2_][a2] = v;
            }
        const float* w = W2 + tid * 6;
        float mu = 0.0f;
#pragma unroll
        for (int d = 0; d < 6; ++d) mu += w[d] * Eh[d];
        float E2 = 0.0f;
#pragma unroll
        for (int a2 = 0; a2 < 6; ++a2)
#pragma unroll
            for (int b2_ = 0; b2_ < 6; ++b2_) E2 += w[a2] * w[b2_] * M[a2][b2_];
        const float var = E2 - mu * mu;
        const float sc = g2[tid] / sqrtf(var + 1e-5f);
        sPar[12 + tid] = sc;
        sPar[15 + tid] = b2[tid] - mu * sc;
    }
}

static __device__ __forceinline__ void bn3_params(const float* __restrict__ sSum,
                                                  const float* __restrict__ W3,
                                                  const float* __restrict__ g3,
                                                  const float* __restrict__ b3,
                                                  float* __restrict__ sPar, int tid) {
    if (tid == 0) {
        const float invN = 1.0f / CNT_F;
        const float Eh0 = sSum[0] * invN, Eh1 = sSum[1] * invN, Eh2 = sSum[2] * invN;
        const float M00 = sSum[3] * invN, M01 = sSum[4] * invN, M02 = sSum[5] * invN;
        const float M11 = sSum[6] * invN, M12 = sSum[7] * invN, M22 = sSum[8] * invN;
        const float w0 = W3[0], w1 = W3[1], w2 = W3[2];
        const float mu = w0 * Eh0 + w1 * Eh1 + w2 * Eh2;
        const float E2 = w0 * w0 * M00 + w1 * w1 * M11 + w2 * w2 * M22 +
                         2.0f * (w0 * w1 * M01 + w0 * w2 * M02 + w1 * w2 * M12);
        const float var = E2 - mu * mu;
        const float sc = g3[0] / sqrtf(var + 1e-5f);
        sPar[0] = sc;
        sPar[1] = b3[0] - mu * sc;
    }
}

static __device__ __forceinline__ void mlp_h1(float s0, float s1, float s2,
                                              const float* __restrict__ W1,
                                              const float* __restrict__ sPar,
                                              float* __restrict__ h1) {
    const float mean = (s0 + s1 + s2) * (1.0f / 3.0f);
    const float f[6] = {s0, s1, s2, s0 - mean, s1 - mean, s2 - mean};
#pragma unroll
    for (int c = 0; c < 6; ++c) {
        float a = 0.0f;
#pragma unroll
        for (int d = 0; d < 6; ++d) a = fmaf(W1[c * 6 + d], f[d], a);
        const float z = fmaf(a, sPar[c], sPar[6 + c]);
        h1[c] = z >= 0.0f ? z : 0.2f * z;
    }
}

static __device__ __forceinline__ void mlp_h2(const float* __restrict__ h1,
                                              const float* __restrict__ W2,
                                              const float* __restrict__ sPar,
                                              float* __restrict__ h2) {
#pragma unroll
    for (int c = 0; c < 3; ++c) {
        float a = 0.0f;
#pragma unroll
        for (int d = 0; d < 6; ++d) a = fmaf(W2[c * 6 + d], h1[d], a);
        const float z = fmaf(a, sPar[12 + c], sPar[15 + c]);
        h2[c] = z >= 0.0f ? z : 0.2f * z;
    }
}

// ---------------------------------------------------------------------------
// Kernel 1: exact KNN + sph/moment tail. R21-proven core (105us: mask+scan
// compaction, separate surv LDS). R22: (a) float4 staging loads (24 scalar
// dword -> 6 dwordx4 per thread; xx op-sequence identical -> bit-exact);
// (b) lm tracked in 4 independent accumulators (max is exact -> same result,
// 64-deep serial chain -> 16).
// ---------------------------------------------------------------------------
__global__ __launch_bounds__(512, 4) void knn_k(const float* __restrict__ xloc,
                                                int* __restrict__ idx_out,
                                                float* __restrict__ sph,   // [3][NROWS]
                                                float* __restrict__ accM,
                                                const float* __restrict__ xg,
                                                float* __restrict__ xT) {
    __shared__ float4 pts[NPTS];              // 64KB
    __shared__ unsigned long long survA[512]; // 4KB: 8 waves x 64 survivors
    __shared__ float msc[72];                 // 8 waves x 9 moment partials

    const int tid  = threadIdx.x;
    const int lane = tid & 63;
    const int wv   = tid >> 6;
    const int b    = blockIdx.y;
    const int n    = (blockIdx.x << 3) + wv;

    // R22 staging: 3 planes as float4 streams (16B-aligned), 2 iters/thread
    const float* xb = xloc + (size_t)b * (3 * NPTS);
    {
        const float4* px = (const float4*)xb;
        const float4* py = (const float4*)(xb + NPTS);
        const float4* pz = (const float4*)(xb + 2 * NPTS);
#pragma unroll
        for (int j = 0; j < 2; ++j) {
            const int i4 = tid + (j << 9);
            const float4 X = px[i4], Y = py[i4], Z = pz[i4];
            pts[(i4 << 2) + 0] = make_float4(X.x, Y.x, Z.x,
                __fadd_rn(__fadd_rn(__fmul_rn(X.x, X.x), __fmul_rn(Y.x, Y.x)), __fmul_rn(Z.x, Z.x)));
            pts[(i4 << 2) + 1] = make_float4(X.y, Y.y, Z.y,
                __fadd_rn(__fadd_rn(__fmul_rn(X.y, X.y), __fmul_rn(Y.y, Y.y)), __fmul_rn(Z.y, Z.y)));
            pts[(i4 << 2) + 2] = make_float4(X.z, Y.z, Z.z,
                __fadd_rn(__fadd_rn(__fmul_rn(X.z, X.z), __fmul_rn(Y.z, Y.z)), __fmul_rn(Z.z, Z.z)));
            pts[(i4 << 2) + 3] = make_float4(X.w, Y.w, Z.w,
                __fadd_rn(__fadd_rn(__fmul_rn(X.w, X.w), __fmul_rn(Y.w, Y.w)), __fmul_rn(Z.w, Z.w)));
        }
    }
    __syncthreads();

    const float4 q = pts[n];

    // distance pass: raw float bits; 4-way lm accumulators (exact max)
    unsigned K[64];
    float lm0 = -3.402823466e38f, lm1 = -3.402823466e38f;
    float lm2 = -3.402823466e38f, lm3 = -3.402823466e38f;
#pragma unroll
    for (int t = 0; t < 64; t += 4) {
#pragma unroll
        for (int u_ = 0; u_ < 4; ++u_) {
            const int tt = t + u_;
            const float4 c = pts[lane + (tt << 6)];
            const float dt = __fadd_rn(__fadd_rn(__fmul_rn(q.x, c.x), __fmul_rn(q.y, c.y)), __fmul_rn(q.z, c.z));
            const float pd = __fsub_rn(__fsub_rn(__fmul_rn(2.0f, dt), q.w), c.w);
            K[tt] = __float_as_uint(pd);
            if (u_ == 0) lm0 = fmaxf(lm0, pd);
            else if (u_ == 1) lm1 = fmaxf(lm1, pd);
            else if (u_ == 2) lm2 = fmaxf(lm2, pd);
            else lm3 = fmaxf(lm3, pd);
        }
    }
    const float lm = fmaxf(fmaxf(lm0, lm1), fmaxf(lm2, lm3));

    // tau = 31st largest lane-max via full bitonic sort (descending) in
    // float domain (finite values, x-x=+0 -> float order == key order)
    float v = lm;
#pragma unroll
    for (int k = 2; k <= 64; k <<= 1) {
#pragma unroll
        for (int j2 = k >> 1; j2 > 0; j2 >>= 1) {
            const float o = __shfl_xor(v, j2, 64);
            const bool keepmax = ((lane & j2) == 0) == ((lane & k) == 0);
            const float mx = v > o ? v : o;
            const float mn = v > o ? o : v;
            v = keepmax ? mx : mn;
        }
    }
    const float tauf = __shfl(v, 30, 64);

    unsigned long long* surv = survA + (wv << 6);
    surv[lane] = 0ULL;

    // per-lane survivor bitmask (no ballots)
    unsigned mLo = 0u, mHi = 0u;
#pragma unroll
    for (int t = 0; t < 32; ++t)
        if (__uint_as_float(K[t]) >= tauf) mLo |= (1u << t);
#pragma unroll
    for (int t = 32; t < 64; ++t)
        if (__uint_as_float(K[t]) >= tauf) mHi |= (1u << (t - 32));
    const int cnt = __popc(mLo) + __popc(mHi);

    // wave inclusive prefix scan of cnt
    int inc = cnt;
#pragma unroll
    for (int o = 1; o < 64; o <<= 1) {
        const int pv = __shfl_up(inc, o, 64);
        if (lane >= o) inc += pv;
    }
    const unsigned total = (unsigned)__shfl(inc, 63, 64);
    int pos = inc - cnt;   // exclusive base for this lane

    // scatter own survivors; pd recomputed with identical op sequence
    unsigned long long mask = ((unsigned long long)mHi << 32) | (unsigned long long)mLo;
    if (pos >= 64) mask = 0ULL;
    while (mask) {
        const int t = (int)(__ffsll((unsigned long long)mask) - 1);
        mask &= mask - 1ULL;
        const float4 c = pts[lane + (t << 6)];
        const float dt = __fadd_rn(__fadd_rn(__fmul_rn(q.x, c.x), __fmul_rn(q.y, c.y)), __fmul_rn(q.z, c.z));
        const float pd = __fsub_rn(__fsub_rn(__fmul_rn(2.0f, dt), q.w), c.w);
        const unsigned u = __float_as_uint(pd);
        const unsigned key = u ^ ((unsigned)((int)u >> 31) | 0x80000000u);
        const unsigned j = (unsigned)(lane + (t << 6));
        surv[pos] = ((unsigned long long)key << 32) | (unsigned)(~j);
        ++pos;
        if (pos >= 64) break;
    }
    __threadfence_block();

    const int bn = (b << 12) + n;
    const size_t obase = (size_t)bn * KSEL;
    int jn = 0;

    if (total <= 64u) {
        unsigned long long s = surv[lane];
#pragma unroll
        for (int k = 2; k <= 64; k <<= 1) {
#pragma unroll
            for (int j2 = k >> 1; j2 > 0; j2 >>= 1) {
                const unsigned long long o = shfl_xor_u64(s, j2);
                const bool keepmax = ((lane & j2) == 0) == ((lane & k) == 0);
                const unsigned long long mx = s > o ? s : o;
                const unsigned long long mn = s > o ? o : s;
                s = keepmax ? mx : mn;
            }
        }
        jn = (int)(~(unsigned)s) & (NPTS - 1);
        if (lane >= KSEL) jn = 0;
    } else {
        // rare fallback: transform all keys in place, then exact radix top-30
#pragma unroll
        for (int t = 0; t < 64; ++t) {
            const unsigned u = K[t];
            K[t] = u ^ ((unsigned)((int)u >> 31) | 0x80000000u);
        }
        unsigned P = 0;
        for (int bit = 31; bit >= 0; --bit) {
            const unsigned cand = P | (1u << bit);
            int c = 0;
#pragma unroll
            for (int t = 0; t < 64; ++t) c += (K[t] >= cand) ? 1 : 0;
#pragma unroll
            for (int o = 32; o > 0; o >>= 1) c += __shfl_xor(c, o, 64);
            if (c >= KSEL) P = cand;
        }
        int* sj = (int*)surv;
        int emitted = 0;
#pragma unroll
        for (int t = 0; t < 64; ++t) {
            const bool g = (K[t] > P);
            const unsigned long long m = __ballot(g);
            if (g) {
                const int p_ = emitted + (int)__popcll(m & ((1ULL << lane) - 1ULL));
                if (p_ < KSEL) sj[p_] = lane + (t << 6);
            }
            emitted += (int)__popcll(m);
        }
#pragma unroll
        for (int t = 0; t < 64; ++t) {
            const bool e_ = (K[t] == P);
            const unsigned long long m = __ballot(e_);
            const int before = (int)__popcll(m & ((1ULL << lane) - 1ULL));
            if (e_ && (emitted + before) < KSEL) sj[emitted + before] = lane + (t << 6);
            emitted += (int)__popcll(m);
        }
        __threadfence_block();
        if (lane < KSEL) jn = sj[lane];
    }

    float s0 = 0.0f, s1 = 0.0f, s2 = 0.0f;
    if (lane < KSEL) {
        idx_out[obase + lane] = jn;
        const float4 c = pts[jn];   // pts fully live (surv is separate LDS)
        const float xr = c.x - q.x, yr = c.y - q.y, zr = c.z - q.z;
        const float sxy2 = xr * xr + yr * yr;
        const float r2   = sxy2 + zr * zr;
        const float rho  = sqrtf(fmaxf(r2, 1e-20f));
        const float sxy  = sqrtf(fmaxf(sxy2, 1e-20f));
        const bool dr = r2 < 1e-20f;
        const bool dp = sxy2 < 1e-20f;
        const float theta = atan2f(dr ? 0.0f : zr, dr ? 1.0f : sxy);
        const float phi   = atan2f(dp ? 0.0f : yr, dp ? 1.0f : xr);
        sph[obase + lane]             = rho;
        sph[NROWS + obase + lane]     = theta;
        sph[2 * NROWS + obase + lane] = phi;
        s0 = rho; s1 = theta; s2 = phi;
    }

    float mom[9] = {s0, s1, s2, s0 * s0, s0 * s1, s0 * s2, s1 * s1, s1 * s2, s2 * s2};
#pragma unroll
    for (int o = 32; o > 0; o >>= 1) {
#pragma unroll
        for (int m = 0; m < 9; ++m) mom[m] += __shfl_xor(mom[m], o, 64);
    }
    if (lane == 0) {
#pragma unroll
        for (int m = 0; m < 9; ++m) msc[wv * 9 + m] = mom[m];
    }
    __syncthreads();
    if (tid < 9) {
        float t_ = 0.0f;
#pragma unroll
        for (int w = 0; w < 8; ++w) t_ += msc[w * 9 + tid];
        atomicAdd(&accM[tid * 64 + ((blockIdx.y * 512 + blockIdx.x) & 63)], t_);
    }

    // transpose side-job — one 64x64 tile per (blockIdx.x<64, batch y).
    // pts LDS is dead here; reuse as 64x65 float tile. Wave-uniform branch.
    if (blockIdx.x < 64) {
        __syncthreads();
        float* tile = (float*)pts;
        const int n0 = (int)blockIdx.x << 6;
        const int tx = tid & 63;
        const int ty = tid >> 6;       // 0..7
        const float* xs = xg + ((size_t)b << 18);
#pragma unroll
        for (int i = 0; i < 8; ++i) {
            const int c = (i << 3) + ty;
            tile[c * 65 + tx] = xs[((size_t)c << 12) + n0 + tx];
        }
        __syncthreads();
        float* ob = xT + ((size_t)b << 18);
#pragma unroll
        for (int i = 0; i < 8; ++i) {
            const int nl = (i << 3) + ty;
            ob[((size_t)(n0 + nl) << 6) + tx] = tile[tx * 65 + nl];
        }
    }
}

// ---------------------------------------------------------------------------
// Kernel 2: h1 moments (27). R22: row-quad processing — each thread handles
// 2 x 4-consecutive rows via 3x dwordx4 plane loads (24 scalar loads -> 6
// vector loads; 8 -> 2 latency round-trips at 1.9 waves/SIMD).
// ---------------------------------------------------------------------------
__global__ __launch_bounds__(256) void p2_k(const float* __restrict__ sph,
                                            const float* __restrict__ W1,
                                            const float* __restrict__ g1,
                                            const float* __restrict__ b1,
                                            const float* __restrict__ accM,
                                            float* __restrict__ acc2) {
    __shared__ float sSum[9];
    __shared__ float sPar[12];
    __shared__ float red[4][27];
    const int tid = threadIdx.x;
    slot_reduce<9>(accM, sSum, tid);
    __syncthreads();
    bn1_params(sSum, W1, g1, b1, sPar, tid);
    __syncthreads();

    float m27[27];
#pragma unroll
    for (int m = 0; m < 27; ++m) m27[m] = 0.0f;
#pragma unroll
    for (int s = 0; s < 2; ++s) {
        const size_t qd = (size_t)blockIdx.x * 256 + tid + (size_t)s * P23_QSTRIDE;
        const float4 A = *(const float4*)(sph + 4 * qd);
        const float4 B = *(const float4*)(sph + NROWS + 4 * qd);
        const float4 C = *(const float4*)(sph + 2 * (size_t)NROWS + 4 * qd);
        const float r0[4] = {A.x, A.y, A.z, A.w};
        const float r1[4] = {B.x, B.y, B.z, B.w};
        const float r2[4] = {C.x, C.y, C.z, C.w};
#pragma unroll
        for (int e = 0; e < 4; ++e) {
            float h1[6];
            mlp_h1(r0[e], r1[e], r2[e], W1, sPar, h1);
            int qq = 6;
#pragma unroll
            for (int a2 = 0; a2 < 6; ++a2) {
                m27[a2] += h1[a2];
#pragma unroll
                for (int b2_ = a2; b2_ < 6; ++b2_) m27[qq++] += h1[a2] * h1[b2_];
            }
        }
    }
#pragma unroll
    for (int o = 32; o > 0; o >>= 1) {
#pragma unroll
        for (int m = 0; m < 27; ++m) m27[m] += __shfl_xor(m27[m], o, 64);
    }
    const int lane = tid & 63, wv = tid >> 6;
    if (lane == 0) {
#pragma unroll
        for (int m = 0; m < 27; ++m) red[wv][m] = m27[m];
    }
    __syncthreads();
    if (tid < 27) {
        const float v = red[0][tid] + red[1][tid] + red[2][tid] + red[3][tid];
        atomicAdd(&acc2[tid * 64 + (blockIdx.x & 63)], v);
    }
}

// ---------------------------------------------------------------------------
// Kernel 3: h2 moments (9) + y3 store. R22: row-quad loads + float4 y3 store.
// ---------------------------------------------------------------------------
__global__ __launch_bounds__(256) void p3_k(const float* __restrict__ sph,
                                            const float* __restrict__ W1,
                                            const float* __restrict__ g1,
                                            const float* __restrict__ b1,
                                            const float* __restrict__ W2,
                                            const float* __restrict__ g2,
                                            const float* __restrict__ b2,
                                            const float* __restrict__ W3,
                                            const float* __restrict__ accM,
                                            const float* __restrict__ acc2,
                                            float* __restrict__ acc3,
                                            float* __restrict__ y3) {
    __shared__ float sSum[27];
    __shared__ float sPar[18];
    __shared__ float red[4][9];
    const int tid = threadIdx.x;
    slot_reduce<9>(accM, sSum, tid);
    __syncthreads();
    bn1_params(sSum, W1, g1, b1, sPar, tid);
    __syncthreads();
    slot_reduce<27>(acc2, sSum, tid);
    __syncthreads();
    bn2_params(sSum, W2, g2, b2, sPar, tid);
    __syncthreads();

    const float w30 = W3[0], w31 = W3[1], w32 = W3[2];

    float m9[9];
#pragma unroll
    for (int m = 0; m < 9; ++m) m9[m] = 0.0f;
#pragma unroll
    for (int s = 0; s < 2; ++s) {
        const size_t qd = (size_t)blockIdx.x * 256 + tid + (size_t)s * P23_QSTRIDE;
        const float4 A = *(const float4*)(sph + 4 * qd);
        const float4 B = *(const float4*)(sph + NROWS + 4 * qd);
        const float4 C = *(const float4*)(sph + 2 * (size_t)NROWS + 4 * qd);
        const float r0[4] = {A.x, A.y, A.z, A.w};
        const float r1[4] = {B.x, B.y, B.z, B.w};
        const float r2[4] = {C.x, C.y, C.z, C.w};
        float yv[4];
#pragma unroll
        for (int e = 0; e < 4; ++e) {
            float h1[6], h2[3];
            mlp_h1(r0[e], r1[e], r2[e], W1, sPar, h1);
            mlp_h2(h1, W2, sPar, h2);
            yv[e] = fmaf(w30, h2[0], fmaf(w31, h2[1], w32 * h2[2]));
            m9[0] += h2[0]; m9[1] += h2[1]; m9[2] += h2[2];
            m9[3] += h2[0] * h2[0]; m9[4] += h2[0] * h2[1]; m9[5] += h2[0] * h2[2];
            m9[6] += h2[1] * h2[1]; m9[7] += h2[1] * h2[2]; m9[8] += h2[2] * h2[2];
        }
        *(float4*)(y3 + 4 * qd) = make_float4(yv[0], yv[1], yv[2], yv[3]);
    }
#pragma unroll
    for (int o = 32; o > 0; o >>= 1) {
#pragma unroll
        for (int m = 0; m < 9; ++m) m9[m] += __shfl_xor(m9[m], o, 64);
    }
    const int lane = tid & 63, wv = tid >> 6;
    if (lane == 0) {
#pragma unroll
        for (int m = 0; m < 9; ++m) red[wv][m] = m9[m];
    }
    __syncthreads();
    if (tid < 9) {
        const float v = red[0][tid] + red[1][tid] + red[2][tid] + red[3][tid];
        atomicAdd(&acc3[tid * 64 + (blockIdx.x & 63)], v);
    }
}

// ---------------------------------------------------------------------------
// Kernel 4: att = lrelu(BN3(y3)), softmax, gather, residual out.
// R13-proven: 4 lane-groups x float4 loads, cross-group butterfly combine.
// ---------------------------------------------------------------------------
__global__ __launch_bounds__(256) void p4_k(const float* __restrict__ y3,
                                            const int* __restrict__ idx,
                                            const float* __restrict__ x,
                                            const float* __restrict__ xT,
                                            const float* __restrict__ W3,
                                            const float* __restrict__ g3,
                                            const float* __restrict__ b3,
                                            const float* __restrict__ acc3,
                                            float* __restrict__ out) {
    __shared__ float sSum[9];
    __shared__ float sPar[2];
    __shared__ float agg[32][65];
    const int tid = threadIdx.x;
    slot_reduce<9>(acc3, sSum, tid);
    __syncthreads();
    bn3_params(sSum, W3, g3, b3, sPar, tid);
    __syncthreads();
    const float sc3 = sPar[0], tb3 = sPar[1];

    const int lane = tid & 63, wv = tid >> 6;
    const int b    = blockIdx.x & 7;         // XCD swizzle: one batch per XCD
    const int n0   = (blockIdx.x >> 3) << 5; // 32 consecutive points within batch
    const int p0   = (b << 12) + n0;
    const float* xTb = xT + ((size_t)b << 18);
    const int g  = lane >> 4;          // neighbor-slot group 0..3
    const int c4 = (lane & 15) << 2;   // channel base (float4)

    for (int i = 0; i < 8; ++i) {
        const int pl = (wv << 3) + i;
        const int p  = p0 + pl;
        float a = -3.4e38f;
        int jn = 0;
        if (lane < KSEL) {
            const size_t r = (size_t)p * KSEL + lane;
            const float z = fmaf(y3[r], sc3, tb3);
            a = z >= 0.0f ? z : 0.2f * z;
            jn = idx[r];
        }
        float mx = a;
#pragma unroll
        for (int o = 32; o > 0; o >>= 1) mx = fmaxf(mx, __shfl_xor(mx, o, 64));
        const float e = (lane < KSEL) ? expf(a - mx) : 0.0f;
        float se = e;
#pragma unroll
        for (int o = 32; o > 0; o >>= 1) se += __shfl_xor(se, o, 64);
        const float w = e / se;   // w==0 for lanes 30..63 -> slots 30,31 are no-ops

        float ax = 0.0f, ay = 0.0f, az = 0.0f, aw = 0.0f;
#pragma unroll
        for (int r8 = 0; r8 < 8; ++r8) {
            const int t = (r8 << 2) + g;                 // neighbor slot 0..31
            const int   j  = __shfl(jn, t, 64);
            const float wt = __shfl(w,  t, 64);
            const float4 v = *reinterpret_cast<const float4*>(xTb + ((size_t)j << 6) + c4);
            ax = fmaf(wt, v.x, ax); ay = fmaf(wt, v.y, ay);
            az = fmaf(wt, v.z, az); aw = fmaf(wt, v.w, aw);
        }
        // combine 4 groups (lanes l, l^16, l^32, l^48 hold same channels)
        ax += __shfl_xor(ax, 32, 64); ay += __shfl_xor(ay, 32, 64);
        az += __shfl_xor(az, 32, 64); aw += __shfl_xor(aw, 32, 64);
        ax += __shfl_xor(ax, 16, 64); ay += __shfl_xor(ay, 16, 64);
        az += __shfl_xor(az, 16, 64); aw += __shfl_xor(aw, 16, 64);
        if (g == 0) {
            agg[pl][c4]     = ax; agg[pl][c4 + 1] = ay;
            agg[pl][c4 + 2] = az; agg[pl][c4 + 3] = aw;
        }
    }
    __syncthreads();

    const float* xb = x + ((size_t)b << 18);
    float* ob = out + ((size_t)b << 18);
    const int nl = tid & 31, cb = tid >> 5;
#pragma unroll
    for (int i = 0; i < 8; ++i) {
        const int c = (i << 3) + cb;
        const size_t off = ((size_t)c << 12) + n0 + nl;
        ob[off] = xb[off] + agg[nl][c];
    }
}

// ---------------------------------------------------------------------------
extern "C" void kernel_launch(void* const* d_in, const int* in_sizes, int n_in,
                              void* d_out, int out_size, void* d_ws, size_t ws_size,
                              hipStream_t stream) {
    const float* x_loc = (const float*)d_in[0];
    const float* x     = (const float*)d_in[1];
    const float* W1    = (const float*)d_in[2];
    const float* g1    = (const float*)d_in[3];
    const float* b1    = (const float*)d_in[4];
    const float* W2    = (const float*)d_in[5];
    const float* g2    = (const float*)d_in[6];
    const float* b2    = (const float*)d_in[7];
    const float* W3    = (const float*)d_in[8];
    const float* g3    = (const float*)d_in[9];
    const float* b3    = (const float*)d_in[10];
    float* out = (float*)d_out;

    float* accM = (float*)d_ws;                 //  9*64
    float* acc2 = accM + 576;                   // 27*64
    float* acc3 = acc2 + 1728;                  //  9*64  (acc region = 2880 floats)
    float* sph  = acc3 + 576;                   // 3*NROWS  (16B-aligned: 2880*4 = 11520)
    int*   idx  = (int*)(sph + 3 * (size_t)NROWS);
    float* y3   = (float*)(idx + NROWS);        // NROWS (16B-aligned)
    float* xT   = y3 + NROWS;                   // B*N*C

    hipMemsetAsync(d_ws, 0, 11520, stream);

    knn_k<<<dim3(NPTS / 8, NB), 512, 0, stream>>>(x_loc, idx, sph, accM, x, xT);
    p2_k<<<P23_BLOCKS, 256, 0, stream>>>(sph, W1, g1, b1, accM, acc2);
    p3_k<<<P23_BLOCKS, 256, 0, stream>>>(sph, W1, g1, b1, W2, g2, b2, W3, accM, acc2, acc3, y3);
    p4_k<<<(NB * NPTS) / 32, 256, 0, stream>>>(y3, idx, x, xT, W3, g3, b3, acc3, out);
}

// Round 11
// 221.511 us; speedup vs baseline: 1.0356x; 1.0356x over previous
//
#include <hip/hip_runtime.h>
#include <math.h>

#define NPTS 4096
#define NB   8
#define NC   64
#define KSEL 30
#define NROWS (NB * NPTS * KSEL)   // 983040
#define CNT_F 983040.0f
#define P23_BLOCKS 480
#define P23_QSTRIDE (P23_BLOCKS * 256)  // 122880 quads; x2 = 245760 quads = NROWS/4

static __device__ __forceinline__ unsigned long long shfl_xor_u64(unsigned long long v, int lx) {
    int lo = __shfl_xor((int)(unsigned)(v & 0xFFFFFFFFULL), lx, 64);
    int hi = __shfl_xor((int)(unsigned)(v >> 32), lx, 64);
    return ((unsigned long long)(unsigned)hi << 32) | (unsigned)lo;
}

// ---------------------------------------------------------------------------
// helpers: per-block reduction of 64-spread accumulator slots, BN param math
// ---------------------------------------------------------------------------
template <int NM>
static __device__ __forceinline__ void slot_reduce(const float* __restrict__ acc,
                                                   float* __restrict__ sSum, int tid) {
    if (tid < 64) {
        float pm[NM];
#pragma unroll
        for (int m = 0; m < NM; ++m) pm[m] = acc[m * 64 + tid];
#pragma unroll
        for (int o = 32; o > 0; o >>= 1) {
#pragma unroll
            for (int m = 0; m < NM; ++m) pm[m] += __shfl_xor(pm[m], o, 64);
        }
        if (tid == 0) {
#pragma unroll
            for (int m = 0; m < NM; ++m) sSum[m] = pm[m];
        }
    }
}

static __device__ __forceinline__ void bn1_params(const float* __restrict__ sSum,
                                                  const float* __restrict__ W1,
                                                  const float* __restrict__ g1,
                                                  const float* __restrict__ b1,
                                                  float* __restrict__ sPar, int tid) {
    if (tid < 6) {
        const float invN = 1.0f / CNT_F;
        const float m0 = sSum[0] * invN, m1 = sSum[1] * invN, m2 = sSum[2] * invN;
        const float E00 = sSum[3] * invN, E01 = sSum[4] * invN, E02 = sSum[5] * invN;
        const float E11 = sSum[6] * invN, E12 = sSum[7] * invN, E22 = sSum[8] * invN;
        const float* w = W1 + tid * 6;
        const float third = (w[3] + w[4] + w[5]) * (1.0f / 3.0f);
        const float a0 = w[0] + w[3] - third;
        const float a1 = w[1] + w[4] - third;
        const float a2 = w[2] + w[5] - third;
        const float mu = a0 * m0 + a1 * m1 + a2 * m2;
        const float E2 = a0 * a0 * E00 + a1 * a1 * E11 + a2 * a2 * E22 +
                         2.0f * (a0 * a1 * E01 + a0 * a2 * E02 + a1 * a2 * E12);
        const float var = E2 - mu * mu;
        const float sc = g1[tid] / sqrtf(var + 1e-5f);
        sPar[tid] = sc;
        sPar[6 + tid] = b1[tid] - mu * sc;
    }
}

static __device__ __forceinline__ void bn2_params(const float* __restrict__ sSum,
                                                  const float* __restrict__ W2,
                                                  const float* __restrict__ g2,
                                                  const float* __restrict__ b2,
                                                  float* __restrict__ sPar, int tid) {
    if (tid < 3) {
        const float invN = 1.0f / CNT_F;
        float Eh[6];
#pragma unroll
        for (int d = 0; d < 6; ++d) Eh[d] = sSum[d] * invN;
        float M[6][6];
        int q = 6;
#pragma unroll
        for (int a2 = 0; a2 < 6; ++a2)
#pragma unroll
            for (int b2_ = a2; b2_ < 6; ++b2_) {
                const float v = sSum[q++] * invN;
                M[a2][b2_] = v; M[b2_][a2] = v;
            }
        const float* w = W2 + tid * 6;
        float mu = 0.0f;
#pragma unroll
        for (int d = 0; d < 6; ++d) mu += w[d] * Eh[d];
        float E2 = 0.0f;
#pragma unroll
        for (int a2 = 0; a2 < 6; ++a2)
#pragma unroll
            for (int b2_ = 0; b2_ < 6; ++b2_) E2 += w[a2] * w[b2_] * M[a2][b2_];
        const float var = E2 - mu * mu;
        const float sc = g2[tid] / sqrtf(var + 1e-5f);
        sPar[12 + tid] = sc;
        sPar[15 + tid] = b2[tid] - mu * sc;
    }
}

static __device__ __forceinline__ void bn3_params(const float* __restrict__ sSum,
                                                  const float* __restrict__ W3,
                                                  const float* __restrict__ g3,
                                                  const float* __restrict__ b3,
                                                  float* __restrict__ sPar, int tid) {
    if (tid == 0) {
        const float invN = 1.0f / CNT_F;
        const float Eh0 = sSum[0] * invN, Eh1 = sSum[1] * invN, Eh2 = sSum[2] * invN;
        const float M00 = sSum[3] * invN, M01 = sSum[4] * invN, M02 = sSum[5] * invN;
        const float M11 = sSum[6] * invN, M12 = sSum[7] * invN, M22 = sSum[8] * invN;
        const float w0 = W3[0], w1 = W3[1], w2 = W3[2];
        const float mu = w0 * Eh0 + w1 * Eh1 + w2 * Eh2;
        const float E2 = w0 * w0 * M00 + w1 * w1 * M11 + w2 * w2 * M22 +
                         2.0f * (w0 * w1 * M01 + w0 * w2 * M02 + w1 * w2 * M12);
        const float var = E2 - mu * mu;
        const float sc = g3[0] / sqrtf(var + 1e-5f);
        sPar[0] = sc;
        sPar[1] = b3[0] - mu * sc;
    }
}

static __device__ __forceinline__ void mlp_h1(float s0, float s1, float s2,
                                              const float* __restrict__ W1,
                                              const float* __restrict__ sPar,
                                              float* __restrict__ h1) {
    const float mean = (s0 + s1 + s2) * (1.0f / 3.0f);
    const float f[6] = {s0, s1, s2, s0 - mean, s1 - mean, s2 - mean};
#pragma unroll
    for (int c = 0; c < 6; ++c) {
        float a = 0.0f;
#pragma unroll
        for (int d = 0; d < 6; ++d) a = fmaf(W1[c * 6 + d], f[d], a);
        const float z = fmaf(a, sPar[c], sPar[6 + c]);
        h1[c] = z >= 0.0f ? z : 0.2f * z;
    }
}

static __device__ __forceinline__ void mlp_h2(const float* __restrict__ h1,
                                              const float* __restrict__ W2,
                                              const float* __restrict__ sPar,
                                              float* __restrict__ h2) {
#pragma unroll
    for (int c = 0; c < 3; ++c) {
        float a = 0.0f;
#pragma unroll
        for (int d = 0; d < 6; ++d) a = fmaf(W2[c * 6 + d], h1[d], a);
        const float z = fmaf(a, sPar[12 + c], sPar[15 + c]);
        h2[c] = z >= 0.0f ? z : 0.2f * z;
    }
}

// ---------------------------------------------------------------------------
// Kernel 1: exact KNN + sph/moment tail. R21-proven core (105us: mask+scan
// compaction, separate surv LDS, scalar staging). R23: R22's float4 staging
// REVERTED — it wrote 4 consecutive float4/lane (64B) -> ~32-way LDS write
// conflicts (SQ_LDS_BANK_CONFLICT 198K -> 6.49M, +7us). Scalar staging
// (lane i writes pts[i], 16B lane stride) rotates banks cleanly. Kept from
// R22: lm 4-way split accumulators (VALU-only, exact max).
// ---------------------------------------------------------------------------
__global__ __launch_bounds__(512, 4) void knn_k(const float* __restrict__ xloc,
                                                int* __restrict__ idx_out,
                                                float* __restrict__ sph,   // [3][NROWS]
                                                float* __restrict__ accM,
                                                const float* __restrict__ xg,
                                                float* __restrict__ xT) {
    __shared__ float4 pts[NPTS];              // 64KB
    __shared__ unsigned long long survA[512]; // 4KB: 8 waves x 64 survivors
    __shared__ float msc[72];                 // 8 waves x 9 moment partials

    const int tid  = threadIdx.x;
    const int lane = tid & 63;
    const int wv   = tid >> 6;
    const int b    = blockIdx.y;
    const int n    = (blockIdx.x << 3) + wv;

    // R21-exact staging: scalar plane loads, lane-stride-16B LDS writes
    const float* xb = xloc + (size_t)b * (3 * NPTS);
    for (int i = tid; i < NPTS; i += 512) {
        const float x = xb[i], y = xb[NPTS + i], z = xb[2 * NPTS + i];
        const float xx = __fadd_rn(__fadd_rn(__fmul_rn(x, x), __fmul_rn(y, y)), __fmul_rn(z, z));
        pts[i] = make_float4(x, y, z, xx);
    }
    __syncthreads();

    const float4 q = pts[n];

    // distance pass: raw float bits; 4-way lm accumulators (exact max)
    unsigned K[64];
    float lm0 = -3.402823466e38f, lm1 = -3.402823466e38f;
    float lm2 = -3.402823466e38f, lm3 = -3.402823466e38f;
#pragma unroll
    for (int t = 0; t < 64; t += 4) {
#pragma unroll
        for (int u_ = 0; u_ < 4; ++u_) {
            const int tt = t + u_;
            const float4 c = pts[lane + (tt << 6)];
            const float dt = __fadd_rn(__fadd_rn(__fmul_rn(q.x, c.x), __fmul_rn(q.y, c.y)), __fmul_rn(q.z, c.z));
            const float pd = __fsub_rn(__fsub_rn(__fmul_rn(2.0f, dt), q.w), c.w);
            K[tt] = __float_as_uint(pd);
            if (u_ == 0) lm0 = fmaxf(lm0, pd);
            else if (u_ == 1) lm1 = fmaxf(lm1, pd);
            else if (u_ == 2) lm2 = fmaxf(lm2, pd);
            else lm3 = fmaxf(lm3, pd);
        }
    }
    const float lm = fmaxf(fmaxf(lm0, lm1), fmaxf(lm2, lm3));

    // tau = 31st largest lane-max via full bitonic sort (descending) in
    // float domain (finite values, x-x=+0 -> float order == key order)
    float v = lm;
#pragma unroll
    for (int k = 2; k <= 64; k <<= 1) {
#pragma unroll
        for (int j2 = k >> 1; j2 > 0; j2 >>= 1) {
            const float o = __shfl_xor(v, j2, 64);
            const bool keepmax = ((lane & j2) == 0) == ((lane & k) == 0);
            const float mx = v > o ? v : o;
            const float mn = v > o ? o : v;
            v = keepmax ? mx : mn;
        }
    }
    const float tauf = __shfl(v, 30, 64);

    unsigned long long* surv = survA + (wv << 6);
    surv[lane] = 0ULL;

    // per-lane survivor bitmask (no ballots)
    unsigned mLo = 0u, mHi = 0u;
#pragma unroll
    for (int t = 0; t < 32; ++t)
        if (__uint_as_float(K[t]) >= tauf) mLo |= (1u << t);
#pragma unroll
    for (int t = 32; t < 64; ++t)
        if (__uint_as_float(K[t]) >= tauf) mHi |= (1u << (t - 32));
    const int cnt = __popc(mLo) + __popc(mHi);

    // wave inclusive prefix scan of cnt
    int inc = cnt;
#pragma unroll
    for (int o = 1; o < 64; o <<= 1) {
        const int pv = __shfl_up(inc, o, 64);
        if (lane >= o) inc += pv;
    }
    const unsigned total = (unsigned)__shfl(inc, 63, 64);
    int pos = inc - cnt;   // exclusive base for this lane

    // scatter own survivors; pd recomputed with identical op sequence
    unsigned long long mask = ((unsigned long long)mHi << 32) | (unsigned long long)mLo;
    if (pos >= 64) mask = 0ULL;
    while (mask) {
        const int t = (int)(__ffsll((unsigned long long)mask) - 1);
        mask &= mask - 1ULL;
        const float4 c = pts[lane + (t << 6)];
        const float dt = __fadd_rn(__fadd_rn(__fmul_rn(q.x, c.x), __fmul_rn(q.y, c.y)), __fmul_rn(q.z, c.z));
        const float pd = __fsub_rn(__fsub_rn(__fmul_rn(2.0f, dt), q.w), c.w);
        const unsigned u = __float_as_uint(pd);
        const unsigned key = u ^ ((unsigned)((int)u >> 31) | 0x80000000u);
        const unsigned j = (unsigned)(lane + (t << 6));
        surv[pos] = ((unsigned long long)key << 32) | (unsigned)(~j);
        ++pos;
        if (pos >= 64) break;
    }
    __threadfence_block();

    const int bn = (b << 12) + n;
    const size_t obase = (size_t)bn * KSEL;
    int jn = 0;

    if (total <= 64u) {
        unsigned long long s = surv[lane];
#pragma unroll
        for (int k = 2; k <= 64; k <<= 1) {
#pragma unroll
            for (int j2 = k >> 1; j2 > 0; j2 >>= 1) {
                const unsigned long long o = shfl_xor_u64(s, j2);
                const bool keepmax = ((lane & j2) == 0) == ((lane & k) == 0);
                const unsigned long long mx = s > o ? s : o;
                const unsigned long long mn = s > o ? o : s;
                s = keepmax ? mx : mn;
            }
        }
        jn = (int)(~(unsigned)s) & (NPTS - 1);
        if (lane >= KSEL) jn = 0;
    } else {
        // rare fallback: transform all keys in place, then exact radix top-30
#pragma unroll
        for (int t = 0; t < 64; ++t) {
            const unsigned u = K[t];
            K[t] = u ^ ((unsigned)((int)u >> 31) | 0x80000000u);
        }
        unsigned P = 0;
        for (int bit = 31; bit >= 0; --bit) {
            const unsigned cand = P | (1u << bit);
            int c = 0;
#pragma unroll
            for (int t = 0; t < 64; ++t) c += (K[t] >= cand) ? 1 : 0;
#pragma unroll
            for (int o = 32; o > 0; o >>= 1) c += __shfl_xor(c, o, 64);
            if (c >= KSEL) P = cand;
        }
        int* sj = (int*)surv;
        int emitted = 0;
#pragma unroll
        for (int t = 0; t < 64; ++t) {
            const bool g = (K[t] > P);
            const unsigned long long m = __ballot(g);
            if (g) {
                const int p_ = emitted + (int)__popcll(m & ((1ULL << lane) - 1ULL));
                if (p_ < KSEL) sj[p_] = lane + (t << 6);
            }
            emitted += (int)__popcll(m);
        }
#pragma unroll
        for (int t = 0; t < 64; ++t) {
            const bool e_ = (K[t] == P);
            const unsigned long long m = __ballot(e_);
            const int before = (int)__popcll(m & ((1ULL << lane) - 1ULL));
            if (e_ && (emitted + before) < KSEL) sj[emitted + before] = lane + (t << 6);
            emitted += (int)__popcll(m);
        }
        __threadfence_block();
        if (lane < KSEL) jn = sj[lane];
    }

    float s0 = 0.0f, s1 = 0.0f, s2 = 0.0f;
    if (lane < KSEL) {
        idx_out[obase + lane] = jn;
        const float4 c = pts[jn];   // pts fully live (surv is separate LDS)
        const float xr = c.x - q.x, yr = c.y - q.y, zr = c.z - q.z;
        const float sxy2 = xr * xr + yr * yr;
        const float r2   = sxy2 + zr * zr;
        const float rho  = sqrtf(fmaxf(r2, 1e-20f));
        const float sxy  = sqrtf(fmaxf(sxy2, 1e-20f));
        const bool dr = r2 < 1e-20f;
        const bool dp = sxy2 < 1e-20f;
        const float theta = atan2f(dr ? 0.0f : zr, dr ? 1.0f : sxy);
        const float phi   = atan2f(dp ? 0.0f : yr, dp ? 1.0f : xr);
        sph[obase + lane]             = rho;
        sph[NROWS + obase + lane]     = theta;
        sph[2 * NROWS + obase + lane] = phi;
        s0 = rho; s1 = theta; s2 = phi;
    }

    float mom[9] = {s0, s1, s2, s0 * s0, s0 * s1, s0 * s2, s1 * s1, s1 * s2, s2 * s2};
#pragma unroll
    for (int o = 32; o > 0; o >>= 1) {
#pragma unroll
        for (int m = 0; m < 9; ++m) mom[m] += __shfl_xor(mom[m], o, 64);
    }
    if (lane == 0) {
#pragma unroll
        for (int m = 0; m < 9; ++m) msc[wv * 9 + m] = mom[m];
    }
    __syncthreads();
    if (tid < 9) {
        float t_ = 0.0f;
#pragma unroll
        for (int w = 0; w < 8; ++w) t_ += msc[w * 9 + tid];
        atomicAdd(&accM[tid * 64 + ((blockIdx.y * 512 + blockIdx.x) & 63)], t_);
    }

    // transpose side-job — one 64x64 tile per (blockIdx.x<64, batch y).
    // pts LDS is dead here; reuse as 64x65 float tile. Wave-uniform branch.
    if (blockIdx.x < 64) {
        __syncthreads();
        float* tile = (float*)pts;
        const int n0 = (int)blockIdx.x << 6;
        const int tx = tid & 63;
        const int ty = tid >> 6;       // 0..7
        const float* xs = xg + ((size_t)b << 18);
#pragma unroll
        for (int i = 0; i < 8; ++i) {
            const int c = (i << 3) + ty;
            tile[c * 65 + tx] = xs[((size_t)c << 12) + n0 + tx];
        }
        __syncthreads();
        float* ob = xT + ((size_t)b << 18);
#pragma unroll
        for (int i = 0; i < 8; ++i) {
            const int nl = (i << 3) + ty;
            ob[((size_t)(n0 + nl) << 6) + tx] = tile[tx * 65 + nl];
        }
    }
}

// ---------------------------------------------------------------------------
// Kernel 2: h1 moments (27). Row-quad processing (R22-neutral, kept): each
// thread handles 2 x 4-consecutive rows via 3x dwordx4 plane loads.
// ---------------------------------------------------------------------------
__global__ __launch_bounds__(256) void p2_k(const float* __restrict__ sph,
                                            const float* __restrict__ W1,
                                            const float* __restrict__ g1,
                                            const float* __restrict__ b1,
                                            const float* __restrict__ accM,
                                            float* __restrict__ acc2) {
    __shared__ float sSum[9];
    __shared__ float sPar[12];
    __shared__ float red[4][27];
    const int tid = threadIdx.x;
    slot_reduce<9>(accM, sSum, tid);
    __syncthreads();
    bn1_params(sSum, W1, g1, b1, sPar, tid);
    __syncthreads();

    float m27[27];
#pragma unroll
    for (int m = 0; m < 27; ++m) m27[m] = 0.0f;
#pragma unroll
    for (int s = 0; s < 2; ++s) {
        const size_t qd = (size_t)blockIdx.x * 256 + tid + (size_t)s * P23_QSTRIDE;
        const float4 A = *(const float4*)(sph + 4 * qd);
        const float4 B = *(const float4*)(sph + NROWS + 4 * qd);
        const float4 C = *(const float4*)(sph + 2 * (size_t)NROWS + 4 * qd);
        const float r0[4] = {A.x, A.y, A.z, A.w};
        const float r1[4] = {B.x, B.y, B.z, B.w};
        const float r2[4] = {C.x, C.y, C.z, C.w};
#pragma unroll
        for (int e = 0; e < 4; ++e) {
            float h1[6];
            mlp_h1(r0[e], r1[e], r2[e], W1, sPar, h1);
            int qq = 6;
#pragma unroll
            for (int a2 = 0; a2 < 6; ++a2) {
                m27[a2] += h1[a2];
#pragma unroll
                for (int b2_ = a2; b2_ < 6; ++b2_) m27[qq++] += h1[a2] * h1[b2_];
            }
        }
    }
#pragma unroll
    for (int o = 32; o > 0; o >>= 1) {
#pragma unroll
        for (int m = 0; m < 27; ++m) m27[m] += __shfl_xor(m27[m], o, 64);
    }
    const int lane = tid & 63, wv = tid >> 6;
    if (lane == 0) {
#pragma unroll
        for (int m = 0; m < 27; ++m) red[wv][m] = m27[m];
    }
    __syncthreads();
    if (tid < 27) {
        const float v = red[0][tid] + red[1][tid] + red[2][tid] + red[3][tid];
        atomicAdd(&acc2[tid * 64 + (blockIdx.x & 63)], v);
    }
}

// ---------------------------------------------------------------------------
// Kernel 3: h2 moments (9) + y3 store. Row-quad loads + float4 y3 store.
// ---------------------------------------------------------------------------
__global__ __launch_bounds__(256) void p3_k(const float* __restrict__ sph,
                                            const float* __restrict__ W1,
                                            const float* __restrict__ g1,
                                            const float* __restrict__ b1,
                                            const float* __restrict__ W2,
                                            const float* __restrict__ g2,
                                            const float* __restrict__ b2,
                                            const float* __restrict__ W3,
                                            const float* __restrict__ accM,
                                            const float* __restrict__ acc2,
                                            float* __restrict__ acc3,
                                            float* __restrict__ y3) {
    __shared__ float sSum[27];
    __shared__ float sPar[18];
    __shared__ float red[4][9];
    const int tid = threadIdx.x;
    slot_reduce<9>(accM, sSum, tid);
    __syncthreads();
    bn1_params(sSum, W1, g1, b1, sPar, tid);
    __syncthreads();
    slot_reduce<27>(acc2, sSum, tid);
    __syncthreads();
    bn2_params(sSum, W2, g2, b2, sPar, tid);
    __syncthreads();

    const float w30 = W3[0], w31 = W3[1], w32 = W3[2];

    float m9[9];
#pragma unroll
    for (int m = 0; m < 9; ++m) m9[m] = 0.0f;
#pragma unroll
    for (int s = 0; s < 2; ++s) {
        const size_t qd = (size_t)blockIdx.x * 256 + tid + (size_t)s * P23_QSTRIDE;
        const float4 A = *(const float4*)(sph + 4 * qd);
        const float4 B = *(const float4*)(sph + NROWS + 4 * qd);
        const float4 C = *(const float4*)(sph + 2 * (size_t)NROWS + 4 * qd);
        const float r0[4] = {A.x, A.y, A.z, A.w};
        const float r1[4] = {B.x, B.y, B.z, B.w};
        const float r2[4] = {C.x, C.y, C.z, C.w};
        float yv[4];
#pragma unroll
        for (int e = 0; e < 4; ++e) {
            float h1[6], h2[3];
            mlp_h1(r0[e], r1[e], r2[e], W1, sPar, h1);
            mlp_h2(h1, W2, sPar, h2);
            yv[e] = fmaf(w30, h2[0], fmaf(w31, h2[1], w32 * h2[2]));
            m9[0] += h2[0]; m9[1] += h2[1]; m9[2] += h2[2];
            m9[3] += h2[0] * h2[0]; m9[4] += h2[0] * h2[1]; m9[5] += h2[0] * h2[2];
            m9[6] += h2[1] * h2[1]; m9[7] += h2[1] * h2[2]; m9[8] += h2[2] * h2[2];
        }
        *(float4*)(y3 + 4 * qd) = make_float4(yv[0], yv[1], yv[2], yv[3]);
    }
#pragma unroll
    for (int o = 32; o > 0; o >>= 1) {
#pragma unroll
        for (int m = 0; m < 9; ++m) m9[m] += __shfl_xor(m9[m], o, 64);
    }
    const int lane = tid & 63, wv = tid >> 6;
    if (lane == 0) {
#pragma unroll
        for (int m = 0; m < 9; ++m) red[wv][m] = m9[m];
    }
    __syncthreads();
    if (tid < 9) {
        const float v = red[0][tid] + red[1][tid] + red[2][tid] + red[3][tid];
        atomicAdd(&acc3[tid * 64 + (blockIdx.x & 63)], v);
    }
}

// ---------------------------------------------------------------------------
// Kernel 4: att = lrelu(BN3(y3)), softmax, gather, residual out.
// R13-proven: 4 lane-groups x float4 loads, cross-group butterfly combine.
// ---------------------------------------------------------------------------
__global__ __launch_bounds__(256) void p4_k(const float* __restrict__ y3,
                                            const int* __restrict__ idx,
                                            const float* __restrict__ x,
                                            const float* __restrict__ xT,
                                            const float* __restrict__ W3,
                                            const float* __restrict__ g3,
                                            const float* __restrict__ b3,
                                            const float* __restrict__ acc3,
                                            float* __restrict__ out) {
    __shared__ float sSum[9];
    __shared__ float sPar[2];
    __shared__ float agg[32][65];
    const int tid = threadIdx.x;
    slot_reduce<9>(acc3, sSum, tid);
    __syncthreads();
    bn3_params(sSum, W3, g3, b3, sPar, tid);
    __syncthreads();
    const float sc3 = sPar[0], tb3 = sPar[1];

    const int lane = tid & 63, wv = tid >> 6;
    const int b    = blockIdx.x & 7;         // XCD swizzle: one batch per XCD
    const int n0   = (blockIdx.x >> 3) << 5; // 32 consecutive points within batch
    const int p0   = (b << 12) + n0;
    const float* xTb = xT + ((size_t)b << 18);
    const int g  = lane >> 4;          // neighbor-slot group 0..3
    const int c4 = (lane & 15) << 2;   // channel base (float4)

    for (int i = 0; i < 8; ++i) {
        const int pl = (wv << 3) + i;
        const int p  = p0 + pl;
        float a = -3.4e38f;
        int jn = 0;
        if (lane < KSEL) {
            const size_t r = (size_t)p * KSEL + lane;
            const float z = fmaf(y3[r], sc3, tb3);
            a = z >= 0.0f ? z : 0.2f * z;
            jn = idx[r];
        }
        float mx = a;
#pragma unroll
        for (int o = 32; o > 0; o >>= 1) mx = fmaxf(mx, __shfl_xor(mx, o, 64));
        const float e = (lane < KSEL) ? expf(a - mx) : 0.0f;
        float se = e;
#pragma unroll
        for (int o = 32; o > 0; o >>= 1) se += __shfl_xor(se, o, 64);
        const float w = e / se;   // w==0 for lanes 30..63 -> slots 30,31 are no-ops

        float ax = 0.0f, ay = 0.0f, az = 0.0f, aw = 0.0f;
#pragma unroll
        for (int r8 = 0; r8 < 8; ++r8) {
            const int t = (r8 << 2) + g;                 // neighbor slot 0..31
            const int   j  = __shfl(jn, t, 64);
            const float wt = __shfl(w,  t, 64);
            const float4 v = *reinterpret_cast<const float4*>(xTb + ((size_t)j << 6) + c4);
            ax = fmaf(wt, v.x, ax); ay = fmaf(wt, v.y, ay);
            az = fmaf(wt, v.z, az); aw = fmaf(wt, v.w, aw);
        }
        // combine 4 groups (lanes l, l^16, l^32, l^48 hold same channels)
        ax += __shfl_xor(ax, 32, 64); ay += __shfl_xor(ay, 32, 64);
        az += __shfl_xor(az, 32, 64); aw += __shfl_xor(aw, 32, 64);
        ax += __shfl_xor(ax, 16, 64); ay += __shfl_xor(ay, 16, 64);
        az += __shfl_xor(az, 16, 64); aw += __shfl_xor(aw, 16, 64);
        if (g == 0) {
            agg[pl][c4]     = ax; agg[pl][c4 + 1] = ay;
            agg[pl][c4 + 2] = az; agg[pl][c4 + 3] = aw;
        }
    }
    __syncthreads();

    const float* xb = x + ((size_t)b << 18);
    float* ob = out + ((size_t)b << 18);
    const int nl = tid & 31, cb = tid >> 5;
#pragma unroll
    for (int i = 0; i < 8; ++i) {
        const int c = (i << 3) + cb;
        const size_t off = ((size_t)c << 12) + n0 + nl;
        ob[off] = xb[off] + agg[nl][c];
    }
}

// ---------------------------------------------------------------------------
extern "C" void kernel_launch(void* const* d_in, const int* in_sizes, int n_in,
                              void* d_out, int out_size, void* d_ws, size_t ws_size,
                              hipStream_t stream) {
    const float* x_loc = (const float*)d_in[0];
    const float* x     = (const float*)d_in[1];
    const float* W1    = (const float*)d_in[2];
    const float* g1    = (const float*)d_in[3];
    const float* b1    = (const float*)d_in[4];
    const float* W2    = (const float*)d_in[5];
    const float* g2    = (const float*)d_in[6];
    const float* b2    = (const float*)d_in[7];
    const float* W3    = (const float*)d_in[8];
    const float* g3    = (const float*)d_in[9];
    const float* b3    = (const float*)d_in[10];
    float* out = (float*)d_out;

    float* accM = (float*)d_ws;                 //  9*64
    float* acc2 = accM + 576;                   // 27*64
    float* acc3 = acc2 + 1728;                  //  9*64  (acc region = 2880 floats)
    float* sph  = acc3 + 576;                   // 3*NROWS  (16B-aligned: 2880*4 = 11520)
    int*   idx  = (int*)(sph + 3 * (size_t)NROWS);
    float* y3   = (float*)(idx + NROWS);        // NROWS (16B-aligned)
    float* xT   = y3 + NROWS;                   // B*N*C

    hipMemsetAsync(d_ws, 0, 11520, stream);

    knn_k<<<dim3(NPTS / 8, NB), 512, 0, stream>>>(x_loc, idx, sph, accM, x, xT);
    p2_k<<<P23_BLOCKS, 256, 0, stream>>>(sph, W1, g1, b1, accM, acc2);
    p3_k<<<P23_BLOCKS, 256, 0, stream>>>(sph, W1, g1, b1, W2, g2, b2, W3, accM, acc2, acc3, y3);
    p4_k<<<(NB * NPTS) / 32, 256, 0, stream>>>(y3, idx, x, xT, W3, g3, b3, acc3, out);
}